// Round 2
// baseline (2831.072 us; speedup 1.0000x reference)
//
#include <hip/hip_runtime.h>
#include <hip/hip_bf16.h>

// ---------------- problem sizes ----------------
#define NB   4096
#define NEXP 16
#define DDIM 256
#define HDIM 1024
#define NCLS 1000

// ---------------- workspace layout (bytes) ----------------
// B  : conv2 out f32 [4096][64][8][8]   67,108,864 B  (offset 0)
// C  : conv3 out f32 [4096][2048]       33,554,432 B
#define OFF_B    ((size_t)0)
#define OFF_C    ((size_t)67108864)
#define OFF_FEAT ((size_t)100663296)   // f32 [4096][256]
#define OFF_MOE  ((size_t)104857600)   // f32 [4096][256]
#define OFF_CNT  ((size_t)109051904)   // int [16]
#define OFF_GSUM ((size_t)109051968)   // f32 [16]
#define OFF_LROW ((size_t)109052032)   // int [16][4096]
#define OFF_LG   ((size_t)109314176)   // f32 [16][4096]
// total ~109.5 MB (same as round 1)

// ================= fused conv1+conv2 per image =================
// x [4096,3,32,32] -> conv3x3(32)+pool+relu (LDS) -> conv3x3(64)+pool+relu -> f32 [4096,64,8,8]
__global__ __launch_bounds__(512) void k_conv12(const float* __restrict__ x,
    const float* __restrict__ w1, const float* __restrict__ b1,
    const float* __restrict__ w2, const float* __restrict__ b2,
    float* __restrict__ outB) {
  __shared__ float xs[3][34][36];     // padded input image
  __shared__ float as[32][18][20];    // padded conv1 pooled output
  __shared__ float ws2[64*288];       // conv2 weights (72 KB)
  __shared__ float ws1[864];
  __shared__ float bs1[32];
  __shared__ float bs2[64];
  const int t = threadIdx.x;
  const int img = blockIdx.x;
  for (int i = t; i < 3*34*36; i += 512) ((float*)xs)[i] = 0.f;
  for (int i = t; i < 32*18*20; i += 512) ((float*)as)[i] = 0.f;
  __syncthreads();
  for (int i = t; i < 3072; i += 512) {
    int ic = i >> 10, rem = i & 1023, y = rem >> 5, xx = rem & 31;
    xs[ic][y+1][xx+1] = x[(size_t)img*3072 + i];
  }
  for (int i = t; i < 864; i += 512) ws1[i] = w1[i];
  for (int i = t; i < 64*288; i += 512) ws2[i] = w2[i];
  if (t < 32) bs1[t] = b1[t];
  else if (t >= 64 && t < 128) bs2[t-64] = b2[t-64];
  __syncthreads();
  // ---- conv1 + pool + relu -> as interior (each thread: 1 pixel x 16 ocs) ----
  {
    const int p = t & 255, grp = t >> 8;
    const int px = p & 15, py = p >> 4;
    float win[3][4][4];
    #pragma unroll
    for (int ic = 0; ic < 3; ++ic)
      #pragma unroll
      for (int r = 0; r < 4; ++r) {
        float2 a  = *(const float2*)&xs[ic][2*py+r][2*px];
        float2 c2 = *(const float2*)&xs[ic][2*py+r][2*px+2];
        win[ic][r][0]=a.x; win[ic][r][1]=a.y; win[ic][r][2]=c2.x; win[ic][r][3]=c2.y;
      }
    for (int occ = grp*16; occ < grp*16 + 16; occ += 8) {
      float acc[8][4];
      #pragma unroll
      for (int j = 0; j < 8; ++j) { float bb = bs1[occ+j]; acc[j][0]=bb;acc[j][1]=bb;acc[j][2]=bb;acc[j][3]=bb; }
      #pragma unroll
      for (int ic = 0; ic < 3; ++ic) {
        #pragma unroll
        for (int j = 0; j < 8; ++j) {
          const float* wp = &ws1[(occ+j)*27 + ic*9];
          float wv[9];
          #pragma unroll
          for (int q = 0; q < 9; ++q) wv[q] = wp[q];   // wave-uniform -> LDS broadcast
          #pragma unroll
          for (int ry = 0; ry < 2; ++ry)
            #pragma unroll
            for (int rx = 0; rx < 2; ++rx) {
              float s = acc[j][ry*2+rx];
              #pragma unroll
              for (int ky = 0; ky < 3; ++ky)
                #pragma unroll
                for (int kx = 0; kx < 3; ++kx)
                  s = fmaf(wv[ky*3+kx], win[ic][ry+ky][rx+kx], s);
              acc[j][ry*2+rx] = s;
            }
        }
      }
      #pragma unroll
      for (int j = 0; j < 8; ++j) {
        float m = fmaxf(fmaxf(acc[j][0],acc[j][1]), fmaxf(acc[j][2],acc[j][3]));
        as[occ+j][py+1][px+1] = fmaxf(m, 0.f);
      }
    }
  }
  __syncthreads();
  // ---- conv2 + pool + relu -> global ----
  {
    const int pix = t & 63, ocg = t >> 6;      // ocg wave-uniform
    const int py = pix >> 3, px = pix & 7;
    float acc[8][4];
    #pragma unroll
    for (int j = 0; j < 8; ++j) { float bb = bs2[j*8+ocg]; acc[j][0]=bb;acc[j][1]=bb;acc[j][2]=bb;acc[j][3]=bb; }
    for (int ic = 0; ic < 32; ++ic) {
      float win[4][4];
      #pragma unroll
      for (int r = 0; r < 4; ++r) {
        float2 a  = *(const float2*)&as[ic][2*py+r][2*px];
        float2 c2 = *(const float2*)&as[ic][2*py+r][2*px+2];
        win[r][0]=a.x; win[r][1]=a.y; win[r][2]=c2.x; win[r][3]=c2.y;
      }
      #pragma unroll
      for (int j = 0; j < 8; ++j) {
        const float* wp = &ws2[(j*8+ocg)*288 + ic*9];
        float wv[9];
        #pragma unroll
        for (int q = 0; q < 9; ++q) wv[q] = wp[q];
        #pragma unroll
        for (int ry = 0; ry < 2; ++ry)
          #pragma unroll
          for (int rx = 0; rx < 2; ++rx) {
            float s = acc[j][ry*2+rx];
            #pragma unroll
            for (int ky = 0; ky < 3; ++ky)
              #pragma unroll
              for (int kx = 0; kx < 3; ++kx)
                s = fmaf(wv[ky*3+kx], win[ry+ky][rx+kx], s);
            acc[j][ry*2+rx] = s;
          }
      }
    }
    const size_t obase = (size_t)img*4096 + (size_t)(py*8 + px);
    #pragma unroll
    for (int j = 0; j < 8; ++j) {
      float m = fmaxf(fmaxf(acc[j][0],acc[j][1]), fmaxf(acc[j][2],acc[j][3]));
      outB[obase + (size_t)(j*8+ocg)*64] = fmaxf(m, 0.f);
    }
  }
}

// ================= conv3: f32 [4096,64,8,8] -> conv3x3(128) -> pool2 -> relu -> f32 [4096,2048]
// grid (4096, 4): blockIdx.y selects 32-oc chunk. ic split over 4 lane-groups, shfl reduce.
__global__ __launch_bounds__(512) void k_conv3(const float* __restrict__ inB,
    const float* __restrict__ w, const float* __restrict__ b,
    float* __restrict__ outC) {
  __shared__ float is[64*10*12];   // padded f32 (30.7 KB)
  __shared__ float ws[32*576];     // 72 KB
  __shared__ float bs[32];
  const int t = threadIdx.x;
  const int img = blockIdx.x, ocb = blockIdx.y;
  for (int i = t; i < 64*120; i += 512) is[i] = 0.f;
  __syncthreads();
  for (int i = t; i < 4096; i += 512) {
    int ic = i >> 6, rem = i & 63, y = rem >> 3, xx = rem & 7;
    is[ic*120 + (y+1)*12 + (xx+1)] = inB[(size_t)img*4096 + i];
  }
  for (int i = t; i < 32*576; i += 512) ws[i] = w[(size_t)ocb*18432 + i];
  if (t < 32) bs[t] = b[ocb*32 + t];
  __syncthreads();
  const int l = t & 63, ocg = t >> 6;      // ocg wave-uniform
  const int pix = l & 15, sub = l >> 4;    // sub partitions ic
  const int py = pix >> 2, px = pix & 3;
  float acc[4][4];
  #pragma unroll
  for (int i = 0; i < 4; ++i) { acc[i][0]=0.f; acc[i][1]=0.f; acc[i][2]=0.f; acc[i][3]=0.f; }
  for (int ict = 0; ict < 16; ++ict) {
    const int ic = sub*16 + ict;
    float win[4][4];
    #pragma unroll
    for (int r = 0; r < 4; ++r) {
      float2 a  = *(const float2*)&is[ic*120 + (2*py+r)*12 + 2*px];
      float2 c2 = *(const float2*)&is[ic*120 + (2*py+r)*12 + 2*px + 2];
      win[r][0]=a.x; win[r][1]=a.y; win[r][2]=c2.x; win[r][3]=c2.y;
    }
    #pragma unroll
    for (int i = 0; i < 4; ++i) {
      const float* wp = &ws[(i*8+ocg)*576 + ic*9];
      float wv[9];
      #pragma unroll
      for (int q = 0; q < 9; ++q) wv[q] = wp[q];
      #pragma unroll
      for (int ry = 0; ry < 2; ++ry)
        #pragma unroll
        for (int rx = 0; rx < 2; ++rx) {
          float s = acc[i][ry*2+rx];
          #pragma unroll
          for (int ky = 0; ky < 3; ++ky)
            #pragma unroll
            for (int kx = 0; kx < 3; ++kx)
              s = fmaf(wv[ky*3+kx], win[ry+ky][rx+kx], s);
          acc[i][ry*2+rx] = s;
        }
    }
  }
  #pragma unroll
  for (int i = 0; i < 4; ++i)
    #pragma unroll
    for (int p = 0; p < 4; ++p) {
      float v = acc[i][p];
      v += __shfl_xor(v, 16, 64);
      v += __shfl_xor(v, 32, 64);
      acc[i][p] = v;
    }
  if (sub == 0) {
    #pragma unroll
    for (int i = 0; i < 4; ++i) {
      float m = fmaxf(fmaxf(acc[i][0],acc[i][1]), fmaxf(acc[i][2],acc[i][3]));
      m = fmaxf(m + bs[i*8+ocg], 0.f);
      outC[(size_t)img*2048 + (size_t)(ocb*32 + i*8 + ocg)*16 + (size_t)(py*4 + px)] = m;
    }
  }
}

// ================= FC (4096x2048 @ 2048x256) + gating (top-2 softmax, expert lists)
__global__ __launch_bounds__(256) void k_fc_gate(const float* __restrict__ C,
    const float* __restrict__ fcw, const float* __restrict__ fcb,
    const float* __restrict__ gw, const float* __restrict__ gb,
    float* __restrict__ feat, int* __restrict__ cnt, float* __restrict__ gsum,
    int* __restrict__ lrow, float* __restrict__ lg) {
  __shared__ float cs[16][128];
  __shared__ float ft[16][256];
  __shared__ float lgs[16][16];
  __shared__ float gwl[4096];
  const int t = threadIdx.x;
  const int r0 = blockIdx.x * 16;
  for (int i = t; i < 4096; i += 256) gwl[i] = gw[i];
  float acc[16];
  {
    float bb = fcb[t];
    #pragma unroll
    for (int r = 0; r < 16; ++r) acc[r] = bb;
  }
  for (int k0 = 0; k0 < 2048; k0 += 128) {
    __syncthreads();
    for (int i = t; i < 2048; i += 256) {
      int r = i >> 7, kk = i & 127;
      cs[r][kk] = C[(size_t)(r0 + r)*2048 + k0 + kk];
    }
    __syncthreads();
    #pragma unroll 8
    for (int kk = 0; kk < 128; ++kk) {
      float wv = fcw[(size_t)(k0+kk)*256 + t];
      #pragma unroll
      for (int r = 0; r < 16; ++r) acc[r] = fmaf(cs[r][kk], wv, acc[r]);
    }
  }
  #pragma unroll
  for (int r = 0; r < 16; ++r) {
    ft[r][t] = acc[r];
    feat[(size_t)(r0+r)*256 + t] = acc[r];
  }
  __syncthreads();
  {
    int r = t >> 4, e = t & 15;
    float s = gb[e];
    for (int k = 0; k < 256; ++k) s = fmaf(ft[r][k], gwl[k*16 + e], s);
    lgs[r][e] = s;
  }
  __syncthreads();
  if (t < 16) {
    int r = t;
    float v1 = -3.402823e38f, v2 = -3.402823e38f;
    int i1 = 0, i2 = 0;
    for (int e = 0; e < 16; ++e) {
      float v = lgs[r][e];
      if (v > v1)      { v2 = v1; i2 = i1; v1 = v; i1 = e; }
      else if (v > v2) { v2 = v;  i2 = e; }
    }
    float ex = __expf(v2 - v1);
    float g1 = 1.f / (1.f + ex);
    float g2 = ex  / (1.f + ex);
    int row = r0 + r;
    int p1 = atomicAdd(&cnt[i1], 1); lrow[i1*4096 + p1] = row; lg[i1*4096 + p1] = g1;
    int p2 = atomicAdd(&cnt[i2], 1); lrow[i2*4096 + p2] = row; lg[i2*4096 + p2] = g2;
    atomicAdd(&gsum[i1], g1);
    atomicAdd(&gsum[i2], g2);
  }
}

// ================= MoE: per-expert grouped rows, 16-row tiles, sparse top-2 (exact)
__global__ __launch_bounds__(256) void k_moe(const float* __restrict__ feat,
    const float* __restrict__ ew1, const float* __restrict__ eb1,
    const float* __restrict__ ew2, const float* __restrict__ eb2,
    const int* __restrict__ cnt, const int* __restrict__ lrow, const float* __restrict__ lgw,
    float* __restrict__ moe) {
  const int e = blockIdx.y;
  const int n_e = cnt[e];
  const int start = blockIdx.x * 16;
  if (start >= n_e) return;
  const int n = min(16, n_e - start);
  __shared__ float fs[16][256];
  __shared__ float t1[16][64];
  __shared__ int   rws[16];
  __shared__ float gws2[16];
  const int t = threadIdx.x;
  if (t < 16) {
    if (t < n) { rws[t] = lrow[e*4096 + start + t]; gws2[t] = lgw[e*4096 + start + t]; }
    else       { rws[t] = 0; gws2[t] = 0.f; }
  }
  __syncthreads();
  for (int i = t; i < 16*256; i += 256) {
    int r = i >> 8, k = i & 255;
    fs[r][k] = (r < n) ? feat[(size_t)rws[r]*256 + k] : 0.f;
  }
  float eo[16];
  #pragma unroll
  for (int r = 0; r < 16; ++r) eo[r] = 0.f;
  const float* w1 = ew1 + (size_t)e*262144;   // [256][1024]
  const float* w2 = ew2 + (size_t)e*262144;   // [1024][256]
  const int h = t & 63, rg = t >> 6;
  for (int hc = 0; hc < 1024; hc += 64) {
    float a[4];
    {
      float bb = eb1[e*1024 + hc + h];
      a[0]=bb; a[1]=bb; a[2]=bb; a[3]=bb;
    }
    __syncthreads();   // t1 free from previous phase-B readers; fs ready on first iter
    #pragma unroll 4
    for (int k = 0; k < 256; ++k) {
      float wv = w1[(size_t)k*1024 + hc + h];
      #pragma unroll
      for (int rr = 0; rr < 4; ++rr) a[rr] = fmaf(fs[rg*4 + rr][k], wv, a[rr]);
    }
    #pragma unroll
    for (int rr = 0; rr < 4; ++rr) t1[rg*4 + rr][h] = fmaxf(a[rr], 0.f);
    __syncthreads();
    #pragma unroll 4
    for (int hh = 0; hh < 64; ++hh) {
      float wv = w2[(size_t)(hc+hh)*256 + t];
      #pragma unroll
      for (int r = 0; r < 16; ++r) eo[r] = fmaf(t1[r][hh], wv, eo[r]);
    }
  }
  float b2 = eb2[e*256 + t];
  for (int r = 0; r < n; ++r)
    atomicAdd(&moe[(size_t)rws[r]*256 + t], gws2[r] * (eo[r] + b2));
}

// ================= load-balance loss
__global__ void k_lb(const float* __restrict__ gsum, float* __restrict__ out_lb) {
  int t = threadIdx.x;
  float term = 0.f;
  if (t < 16) {
    float D = gsum[t] * (1.f/4096.f);
    term = D * logf(D + 1e-8f);
  }
  #pragma unroll
  for (int o = 8; o > 0; o >>= 1) term += __shfl_down(term, o, 64);
  if (t == 0) *out_lb = term;
}

// ================= LayerNorm(moe + feat) in-place into moe
__global__ __launch_bounds__(256) void k_ln(const float* __restrict__ feat,
    float* __restrict__ moe, const float* __restrict__ g, const float* __restrict__ bp) {
  const int r = blockIdx.x, t = threadIdx.x;
  float v = moe[(size_t)r*256 + t] + feat[(size_t)r*256 + t];
  float s = v, q = v * v;
  #pragma unroll
  for (int o = 32; o > 0; o >>= 1) {
    s += __shfl_down(s, o, 64);
    q += __shfl_down(q, o, 64);
  }
  __shared__ float ss[4], qq[4];
  int wv = t >> 6;
  if ((t & 63) == 0) { ss[wv] = s; qq[wv] = q; }
  __syncthreads();
  float S = ss[0]+ss[1]+ss[2]+ss[3];
  float Q = qq[0]+qq[1]+qq[2]+qq[3];
  float mu  = S * (1.f/256.f);
  float var = Q * (1.f/256.f) - mu*mu;
  float inv = rsqrtf(var + 1e-5f);
  moe[(size_t)r*256 + t] = (v - mu) * inv * g[t] + bp[t];
}

// ================= output GEMM: [4096,256] @ [256,1000] + b
__global__ __launch_bounds__(256) void k_out(const float* __restrict__ y,
    const float* __restrict__ ow, const float* __restrict__ ob,
    float* __restrict__ out) {
  __shared__ float ys[32][256];
  const int t = threadIdx.x;
  const int r0 = blockIdx.x * 32;
  const int c = blockIdx.y * 256 + t;
  for (int i = t; i < 32*256; i += 256) {
    int r = i >> 8, k = i & 255;
    ys[r][k] = y[(size_t)(r0+r)*256 + k];
  }
  __syncthreads();
  if (c >= NCLS) return;
  float acc[32];
  {
    float bb = ob[c];
    #pragma unroll
    for (int r = 0; r < 32; ++r) acc[r] = bb;
  }
  #pragma unroll 4
  for (int k = 0; k < 256; ++k) {
    float wv = ow[(size_t)k*NCLS + c];
    #pragma unroll
    for (int r = 0; r < 32; ++r) acc[r] = fmaf(ys[r][k], wv, acc[r]);
  }
  for (int r = 0; r < 32; ++r) out[(size_t)(r0+r)*NCLS + c] = acc[r];
}

// ================= launch =================
extern "C" void kernel_launch(void* const* d_in, const int* in_sizes, int n_in,
                              void* d_out, int out_size, void* d_ws, size_t ws_size,
                              hipStream_t stream) {
  const float* x   = (const float*)d_in[0];
  const float* c1w = (const float*)d_in[1];
  const float* c1b = (const float*)d_in[2];
  const float* c2w = (const float*)d_in[3];
  const float* c2b = (const float*)d_in[4];
  const float* c3w = (const float*)d_in[5];
  const float* c3b = (const float*)d_in[6];
  const float* fcw = (const float*)d_in[7];
  const float* fcb = (const float*)d_in[8];
  const float* gw  = (const float*)d_in[9];
  const float* gb  = (const float*)d_in[10];
  const float* ew1 = (const float*)d_in[11];
  const float* eb1 = (const float*)d_in[12];
  const float* ew2 = (const float*)d_in[13];
  const float* eb2 = (const float*)d_in[14];
  const float* lng = (const float*)d_in[15];
  const float* lnb = (const float*)d_in[16];
  const float* ow  = (const float*)d_in[17];
  const float* ob  = (const float*)d_in[18];
  char* ws = (char*)d_ws;
  float* Bb   = (float*)(ws + OFF_B);
  float* C    = (float*)(ws + OFF_C);
  float* feat = (float*)(ws + OFF_FEAT);
  float* moe  = (float*)(ws + OFF_MOE);
  int*   cnt  = (int*)(ws + OFF_CNT);
  float* gsum = (float*)(ws + OFF_GSUM);
  int*   lrow = (int*)(ws + OFF_LROW);
  float* lgv  = (float*)(ws + OFF_LG);
  float* outp = (float*)d_out;

  // zero moe accumulator + counts + gate sums (contiguous region)
  hipMemsetAsync(ws + OFF_MOE, 0, 4194304 + 128, stream);

  hipLaunchKernelGGL(k_conv12, dim3(4096),   dim3(512), 0, stream, x, c1w, c1b, c2w, c2b, Bb);
  hipLaunchKernelGGL(k_conv3, dim3(4096, 4), dim3(512), 0, stream, Bb, c3w, c3b, C);
  hipLaunchKernelGGL(k_fc_gate, dim3(256),   dim3(256), 0, stream, C, fcw, fcb, gw, gb,
                     feat, cnt, gsum, lrow, lgv);
  hipLaunchKernelGGL(k_moe, dim3(256, 16),   dim3(256), 0, stream, feat, ew1, eb1, ew2, eb2,
                     cnt, lrow, lgv, moe);
  hipLaunchKernelGGL(k_lb,  dim3(1),         dim3(64),  0, stream, gsum, outp + (size_t)NB*NCLS);
  hipLaunchKernelGGL(k_ln,  dim3(4096),      dim3(256), 0, stream, feat, moe, lng, lnb);
  hipLaunchKernelGGL(k_out, dim3(128, 4),    dim3(256), 0, stream, moe, ow, ob, outp);
}

// Round 3
// 2249.088 us; speedup vs baseline: 1.2588x; 1.2588x over previous
//
#include <hip/hip_runtime.h>
#include <hip/hip_bf16.h>

// ---------------- problem sizes ----------------
#define NB   4096
#define NEXP 16
#define DDIM 256
#define HDIM 1024
#define NCLS 1000

// ---------------- workspace layout (bytes) ----------------
// B  : conv2 out f32 [4096][64][8][8]   67,108,864 B  (offset 0)
//      (dead after conv3 -> P0/P1 FC split-K partials alias it)
// C  : conv3 out f32 [4096][2048]       33,554,432 B
#define OFF_B    ((size_t)0)
#define OFF_P0   ((size_t)0)           // f32 [4096][256] FC partial (K half 0)
#define OFF_P1   ((size_t)4194304)     // f32 [4096][256] FC partial (K half 1)
#define OFF_C    ((size_t)67108864)
#define OFF_FEAT ((size_t)100663296)   // f32 [4096][256]
#define OFF_MOE  ((size_t)104857600)   // f32 [4096][256]
#define OFF_CNT  ((size_t)109051904)   // int [16]
#define OFF_GSUM ((size_t)109051968)   // f32 [16]
#define OFF_LROW ((size_t)109052032)   // int [16][4096]
#define OFF_LG   ((size_t)109314176)   // f32 [16][4096]
// total ~109.5 MB (same as round 2)

// ================= fused conv1+conv2 per image =================
__global__ __launch_bounds__(512) void k_conv12(const float* __restrict__ x,
    const float* __restrict__ w1, const float* __restrict__ b1,
    const float* __restrict__ w2, const float* __restrict__ b2,
    float* __restrict__ outB) {
  __shared__ float xs[3][34][36];     // padded input image
  __shared__ float as[32][18][20];    // padded conv1 pooled output
  __shared__ float ws2[64*288];       // conv2 weights (72 KB)
  __shared__ float ws1[864];
  __shared__ float bs1[32];
  __shared__ float bs2[64];
  const int t = threadIdx.x;
  const int img = blockIdx.x;
  for (int i = t; i < 3*34*36; i += 512) ((float*)xs)[i] = 0.f;
  for (int i = t; i < 32*18*20; i += 512) ((float*)as)[i] = 0.f;
  __syncthreads();
  for (int i = t; i < 3072; i += 512) {
    int ic = i >> 10, rem = i & 1023, y = rem >> 5, xx = rem & 31;
    xs[ic][y+1][xx+1] = x[(size_t)img*3072 + i];
  }
  for (int i = t; i < 864; i += 512) ws1[i] = w1[i];
  for (int i = t; i < 64*288; i += 512) ws2[i] = w2[i];
  if (t < 32) bs1[t] = b1[t];
  else if (t >= 64 && t < 128) bs2[t-64] = b2[t-64];
  __syncthreads();
  // ---- conv1 + pool + relu -> as interior ----
  {
    const int p = t & 255, grp = t >> 8;
    const int px = p & 15, py = p >> 4;
    float win[3][4][4];
    #pragma unroll
    for (int ic = 0; ic < 3; ++ic)
      #pragma unroll
      for (int r = 0; r < 4; ++r) {
        float2 a  = *(const float2*)&xs[ic][2*py+r][2*px];
        float2 c2 = *(const float2*)&xs[ic][2*py+r][2*px+2];
        win[ic][r][0]=a.x; win[ic][r][1]=a.y; win[ic][r][2]=c2.x; win[ic][r][3]=c2.y;
      }
    for (int occ = grp*16; occ < grp*16 + 16; occ += 8) {
      float acc[8][4];
      #pragma unroll
      for (int j = 0; j < 8; ++j) { float bb = bs1[occ+j]; acc[j][0]=bb;acc[j][1]=bb;acc[j][2]=bb;acc[j][3]=bb; }
      #pragma unroll
      for (int ic = 0; ic < 3; ++ic) {
        #pragma unroll
        for (int j = 0; j < 8; ++j) {
          const float* wp = &ws1[(occ+j)*27 + ic*9];
          float wv[9];
          #pragma unroll
          for (int q = 0; q < 9; ++q) wv[q] = wp[q];
          #pragma unroll
          for (int ry = 0; ry < 2; ++ry)
            #pragma unroll
            for (int rx = 0; rx < 2; ++rx) {
              float s = acc[j][ry*2+rx];
              #pragma unroll
              for (int ky = 0; ky < 3; ++ky)
                #pragma unroll
                for (int kx = 0; kx < 3; ++kx)
                  s = fmaf(wv[ky*3+kx], win[ic][ry+ky][rx+kx], s);
              acc[j][ry*2+rx] = s;
            }
        }
      }
      #pragma unroll
      for (int j = 0; j < 8; ++j) {
        float m = fmaxf(fmaxf(acc[j][0],acc[j][1]), fmaxf(acc[j][2],acc[j][3]));
        as[occ+j][py+1][px+1] = fmaxf(m, 0.f);
      }
    }
  }
  __syncthreads();
  // ---- conv2 + pool + relu -> global ----
  {
    const int pix = t & 63, ocg = t >> 6;
    const int py = pix >> 3, px = pix & 7;
    float acc[8][4];
    #pragma unroll
    for (int j = 0; j < 8; ++j) { float bb = bs2[j*8+ocg]; acc[j][0]=bb;acc[j][1]=bb;acc[j][2]=bb;acc[j][3]=bb; }
    for (int ic = 0; ic < 32; ++ic) {
      float win[4][4];
      #pragma unroll
      for (int r = 0; r < 4; ++r) {
        float2 a  = *(const float2*)&as[ic][2*py+r][2*px];
        float2 c2 = *(const float2*)&as[ic][2*py+r][2*px+2];
        win[r][0]=a.x; win[r][1]=a.y; win[r][2]=c2.x; win[r][3]=c2.y;
      }
      #pragma unroll
      for (int j = 0; j < 8; ++j) {
        const float* wp = &ws2[(j*8+ocg)*288 + ic*9];
        float wv[9];
        #pragma unroll
        for (int q = 0; q < 9; ++q) wv[q] = wp[q];
        #pragma unroll
        for (int ry = 0; ry < 2; ++ry)
          #pragma unroll
          for (int rx = 0; rx < 2; ++rx) {
            float s = acc[j][ry*2+rx];
            #pragma unroll
            for (int ky = 0; ky < 3; ++ky)
              #pragma unroll
              for (int kx = 0; kx < 3; ++kx)
                s = fmaf(wv[ky*3+kx], win[ry+ky][rx+kx], s);
            acc[j][ry*2+rx] = s;
          }
      }
    }
    const size_t obase = (size_t)img*4096 + (size_t)(py*8 + px);
    #pragma unroll
    for (int j = 0; j < 8; ++j) {
      float m = fmaxf(fmaxf(acc[j][0],acc[j][1]), fmaxf(acc[j][2],acc[j][3]));
      outB[obase + (size_t)(j*8+ocg)*64] = fmaxf(m, 0.f);
    }
  }
}

// ================= conv3: f32 [4096,64,8,8] -> conv3x3(128) -> pool2 -> relu -> f32 [4096,2048]
__global__ __launch_bounds__(512) void k_conv3(const float* __restrict__ inB,
    const float* __restrict__ w, const float* __restrict__ b,
    float* __restrict__ outC) {
  __shared__ float is[64*10*12];
  __shared__ float ws[32*576];
  __shared__ float bs[32];
  const int t = threadIdx.x;
  const int img = blockIdx.x, ocb = blockIdx.y;
  for (int i = t; i < 64*120; i += 512) is[i] = 0.f;
  __syncthreads();
  for (int i = t; i < 4096; i += 512) {
    int ic = i >> 6, rem = i & 63, y = rem >> 3, xx = rem & 7;
    is[ic*120 + (y+1)*12 + (xx+1)] = inB[(size_t)img*4096 + i];
  }
  for (int i = t; i < 32*576; i += 512) ws[i] = w[(size_t)ocb*18432 + i];
  if (t < 32) bs[t] = b[ocb*32 + t];
  __syncthreads();
  const int l = t & 63, ocg = t >> 6;
  const int pix = l & 15, sub = l >> 4;
  const int py = pix >> 2, px = pix & 3;
  float acc[4][4];
  #pragma unroll
  for (int i = 0; i < 4; ++i) { acc[i][0]=0.f; acc[i][1]=0.f; acc[i][2]=0.f; acc[i][3]=0.f; }
  for (int ict = 0; ict < 16; ++ict) {
    const int ic = sub*16 + ict;
    float win[4][4];
    #pragma unroll
    for (int r = 0; r < 4; ++r) {
      float2 a  = *(const float2*)&is[ic*120 + (2*py+r)*12 + 2*px];
      float2 c2 = *(const float2*)&is[ic*120 + (2*py+r)*12 + 2*px + 2];
      win[r][0]=a.x; win[r][1]=a.y; win[r][2]=c2.x; win[r][3]=c2.y;
    }
    #pragma unroll
    for (int i = 0; i < 4; ++i) {
      const float* wp = &ws[(i*8+ocg)*576 + ic*9];
      float wv[9];
      #pragma unroll
      for (int q = 0; q < 9; ++q) wv[q] = wp[q];
      #pragma unroll
      for (int ry = 0; ry < 2; ++ry)
        #pragma unroll
        for (int rx = 0; rx < 2; ++rx) {
          float s = acc[i][ry*2+rx];
          #pragma unroll
          for (int ky = 0; ky < 3; ++ky)
            #pragma unroll
            for (int kx = 0; kx < 3; ++kx)
              s = fmaf(wv[ky*3+kx], win[ry+ky][rx+kx], s);
          acc[i][ry*2+rx] = s;
        }
    }
  }
  #pragma unroll
  for (int i = 0; i < 4; ++i)
    #pragma unroll
    for (int p = 0; p < 4; ++p) {
      float v = acc[i][p];
      v += __shfl_xor(v, 16, 64);
      v += __shfl_xor(v, 32, 64);
      acc[i][p] = v;
    }
  if (sub == 0) {
    #pragma unroll
    for (int i = 0; i < 4; ++i) {
      float m = fmaxf(fmaxf(acc[i][0],acc[i][1]), fmaxf(acc[i][2],acc[i][3]));
      m = fmaxf(m + bs[i*8+ocg], 0.f);
      outC[(size_t)img*2048 + (size_t)(ocb*32 + i*8 + ocg)*16 + (size_t)(py*4 + px)] = m;
    }
  }
}

// ================= FC GEMM: [4096,2048] @ [2048,256], split-K=2, 64x64 tiles, 4x4 micro-tile
// grid (64, 4, 2); P[half] partial sums (no bias). Register-tiled, both operands in LDS.
__global__ __launch_bounds__(256) void k_fc(const float* __restrict__ C,
    const float* __restrict__ fcw, float* __restrict__ P0, float* __restrict__ P1) {
  __shared__ float As[32][68];   // A^T tile: As[k][row], padded
  __shared__ float Bs[32][68];   // B tile:   Bs[k][col], padded
  const int t = threadIdx.x;
  const int r0 = blockIdx.x * 64;
  const int nc = blockIdx.y * 64;
  const int kbase = blockIdx.z * 1024;
  float* __restrict__ P = blockIdx.z ? P1 : P0;
  const int tx = t & 15, ty = t >> 4;
  float acc[4][4];
  #pragma unroll
  for (int i = 0; i < 4; ++i)
    #pragma unroll
    for (int j = 0; j < 4; ++j) acc[i][j] = 0.f;
  // stage indices (2 float4 each for A and B)
  const int ia0 = t*2, ia1 = t*2 + 1;
  for (int c = 0; c < 32; ++c) {
    const int k0 = kbase + c*32;
    __syncthreads();
    // stage A (64 rows x 32 k, transposed into As[k][row])
    #pragma unroll
    for (int j = 0; j < 2; ++j) {
      int idx = (j ? ia1 : ia0);
      int row = idx >> 3, kq = idx & 7;
      float4 v = *(const float4*)&C[(size_t)(r0+row)*2048 + k0 + kq*4];
      As[kq*4+0][row] = v.x; As[kq*4+1][row] = v.y;
      As[kq*4+2][row] = v.z; As[kq*4+3][row] = v.w;
    }
    // stage B (32 k x 64 cols, direct)
    #pragma unroll
    for (int j = 0; j < 2; ++j) {
      int idx = (j ? ia1 : ia0);
      int krow = idx >> 4, c4 = idx & 15;
      float4 v = *(const float4*)&fcw[(size_t)(k0+krow)*256 + nc + c4*4];
      *(float4*)&Bs[krow][c4*4] = v;
    }
    __syncthreads();
    #pragma unroll 8
    for (int k = 0; k < 32; ++k) {
      float4 av = *(const float4*)&As[k][ty*4];
      float4 bv = *(const float4*)&Bs[k][tx*4];
      float a[4] = {av.x, av.y, av.z, av.w};
      float bbv[4] = {bv.x, bv.y, bv.z, bv.w};
      #pragma unroll
      for (int i = 0; i < 4; ++i)
        #pragma unroll
        for (int j = 0; j < 4; ++j)
          acc[i][j] = fmaf(a[i], bbv[j], acc[i][j]);
    }
  }
  #pragma unroll
  for (int i = 0; i < 4; ++i) {
    float4 v = make_float4(acc[i][0], acc[i][1], acc[i][2], acc[i][3]);
    *(float4*)&P[(size_t)(r0 + ty*4 + i)*256 + nc + tx*4] = v;
  }
}

// ================= gate: feat = P0+P1+fcb; logits; top-2 softmax; expert lists
__global__ __launch_bounds__(256) void k_gate(const float* __restrict__ P0,
    const float* __restrict__ P1, const float* __restrict__ fcb,
    const float* __restrict__ gw, const float* __restrict__ gb,
    float* __restrict__ feat, int* __restrict__ cnt, float* __restrict__ gsum,
    int* __restrict__ lrow, float* __restrict__ lg) {
  __shared__ float ft[16][256];
  __shared__ float lgs[16][16];
  __shared__ float gwl[4096];
  const int t = threadIdx.x;
  const int r0 = blockIdx.x * 16;
  for (int i = t; i < 4096; i += 256) gwl[i] = gw[i];
  float bb = fcb[t];
  #pragma unroll
  for (int r = 0; r < 16; ++r) {
    size_t off = (size_t)(r0+r)*256 + t;
    float v = P0[off] + P1[off] + bb;
    ft[r][t] = v;
    feat[off] = v;
  }
  __syncthreads();
  {
    int r = t >> 4, e = t & 15;
    float s = gb[e];
    for (int k = 0; k < 256; ++k) s = fmaf(ft[r][k], gwl[k*16 + e], s);
    lgs[r][e] = s;
  }
  __syncthreads();
  if (t < 16) {
    int r = t;
    float v1 = -3.402823e38f, v2 = -3.402823e38f;
    int i1 = 0, i2 = 0;
    for (int e = 0; e < 16; ++e) {
      float v = lgs[r][e];
      if (v > v1)      { v2 = v1; i2 = i1; v1 = v; i1 = e; }
      else if (v > v2) { v2 = v;  i2 = e; }
    }
    float ex = __expf(v2 - v1);
    float g1 = 1.f / (1.f + ex);
    float g2 = ex  / (1.f + ex);
    int row = r0 + r;
    int p1 = atomicAdd(&cnt[i1], 1); lrow[i1*4096 + p1] = row; lg[i1*4096 + p1] = g1;
    int p2 = atomicAdd(&cnt[i2], 1); lrow[i2*4096 + p2] = row; lg[i2*4096 + p2] = g2;
    atomicAdd(&gsum[i1], g1);
    atomicAdd(&gsum[i2], g2);
  }
}

// ================= MoE: per-expert grouped rows, 16-row tiles, sparse top-2 (exact)
__global__ __launch_bounds__(256) void k_moe(const float* __restrict__ feat,
    const float* __restrict__ ew1, const float* __restrict__ eb1,
    const float* __restrict__ ew2, const float* __restrict__ eb2,
    const int* __restrict__ cnt, const int* __restrict__ lrow, const float* __restrict__ lgw,
    float* __restrict__ moe) {
  const int e = blockIdx.y;
  const int n_e = cnt[e];
  const int start = blockIdx.x * 16;
  if (start >= n_e) return;
  const int n = min(16, n_e - start);
  __shared__ float fs[16][256];
  __shared__ float t1[16][64];
  __shared__ int   rws[16];
  __shared__ float gws2[16];
  const int t = threadIdx.x;
  if (t < 16) {
    if (t < n) { rws[t] = lrow[e*4096 + start + t]; gws2[t] = lgw[e*4096 + start + t]; }
    else       { rws[t] = 0; gws2[t] = 0.f; }
  }
  __syncthreads();
  for (int i = t; i < 16*256; i += 256) {
    int r = i >> 8, k = i & 255;
    fs[r][k] = (r < n) ? feat[(size_t)rws[r]*256 + k] : 0.f;
  }
  float eo[16];
  #pragma unroll
  for (int r = 0; r < 16; ++r) eo[r] = 0.f;
  const float* w1 = ew1 + (size_t)e*262144;
  const float* w2 = ew2 + (size_t)e*262144;
  const int h = t & 63, rg = t >> 6;
  for (int hc = 0; hc < 1024; hc += 64) {
    float a[4];
    {
      float bb = eb1[e*1024 + hc + h];
      a[0]=bb; a[1]=bb; a[2]=bb; a[3]=bb;
    }
    __syncthreads();
    #pragma unroll 4
    for (int k = 0; k < 256; ++k) {
      float wv = w1[(size_t)k*1024 + hc + h];
      #pragma unroll
      for (int rr = 0; rr < 4; ++rr) a[rr] = fmaf(fs[rg*4 + rr][k], wv, a[rr]);
    }
    #pragma unroll
    for (int rr = 0; rr < 4; ++rr) t1[rg*4 + rr][h] = fmaxf(a[rr], 0.f);
    __syncthreads();
    #pragma unroll 4
    for (int hh = 0; hh < 64; ++hh) {
      float wv = w2[(size_t)(hc+hh)*256 + t];
      #pragma unroll
      for (int r = 0; r < 16; ++r) eo[r] = fmaf(t1[r][hh], wv, eo[r]);
    }
  }
  float b2 = eb2[e*256 + t];
  for (int r = 0; r < n; ++r)
    atomicAdd(&moe[(size_t)rws[r]*256 + t], gws2[r] * (eo[r] + b2));
}

// ================= load-balance loss
__global__ void k_lb(const float* __restrict__ gsum, float* __restrict__ out_lb) {
  int t = threadIdx.x;
  float term = 0.f;
  if (t < 16) {
    float D = gsum[t] * (1.f/4096.f);
    term = D * logf(D + 1e-8f);
  }
  #pragma unroll
  for (int o = 8; o > 0; o >>= 1) term += __shfl_down(term, o, 64);
  if (t == 0) *out_lb = term;
}

// ================= LayerNorm(moe + feat) in-place into moe
__global__ __launch_bounds__(256) void k_ln(const float* __restrict__ feat,
    float* __restrict__ moe, const float* __restrict__ g, const float* __restrict__ bp) {
  const int r = blockIdx.x, t = threadIdx.x;
  float v = moe[(size_t)r*256 + t] + feat[(size_t)r*256 + t];
  float s = v, q = v * v;
  #pragma unroll
  for (int o = 32; o > 0; o >>= 1) {
    s += __shfl_down(s, o, 64);
    q += __shfl_down(q, o, 64);
  }
  __shared__ float ss[4], qq[4];
  int wv = t >> 6;
  if ((t & 63) == 0) { ss[wv] = s; qq[wv] = q; }
  __syncthreads();
  float S = ss[0]+ss[1]+ss[2]+ss[3];
  float Q = qq[0]+qq[1]+qq[2]+qq[3];
  float mu  = S * (1.f/256.f);
  float var = Q * (1.f/256.f) - mu*mu;
  float inv = rsqrtf(var + 1e-5f);
  moe[(size_t)r*256 + t] = (v - mu) * inv * g[t] + bp[t];
}

// ================= output GEMM: [4096,256] @ [256,1000] + b
__global__ __launch_bounds__(256) void k_out(const float* __restrict__ y,
    const float* __restrict__ ow, const float* __restrict__ ob,
    float* __restrict__ out) {
  __shared__ float ys[32][256];
  const int t = threadIdx.x;
  const int r0 = blockIdx.x * 32;
  const int c = blockIdx.y * 256 + t;
  for (int i = t; i < 32*256; i += 256) {
    int r = i >> 8, k = i & 255;
    ys[r][k] = y[(size_t)(r0+r)*256 + k];
  }
  __syncthreads();
  if (c >= NCLS) return;
  float acc[32];
  {
    float bb = ob[c];
    #pragma unroll
    for (int r = 0; r < 32; ++r) acc[r] = bb;
  }
  #pragma unroll 4
  for (int k = 0; k < 256; ++k) {
    float wv = ow[(size_t)k*NCLS + c];
    #pragma unroll
    for (int r = 0; r < 32; ++r) acc[r] = fmaf(ys[r][k], wv, acc[r]);
  }
  for (int r = 0; r < 32; ++r) out[(size_t)(r0+r)*NCLS + c] = acc[r];
}

// ================= launch =================
extern "C" void kernel_launch(void* const* d_in, const int* in_sizes, int n_in,
                              void* d_out, int out_size, void* d_ws, size_t ws_size,
                              hipStream_t stream) {
  const float* x   = (const float*)d_in[0];
  const float* c1w = (const float*)d_in[1];
  const float* c1b = (const float*)d_in[2];
  const float* c2w = (const float*)d_in[3];
  const float* c2b = (const float*)d_in[4];
  const float* c3w = (const float*)d_in[5];
  const float* c3b = (const float*)d_in[6];
  const float* fcw = (const float*)d_in[7];
  const float* fcb = (const float*)d_in[8];
  const float* gw  = (const float*)d_in[9];
  const float* gb  = (const float*)d_in[10];
  const float* ew1 = (const float*)d_in[11];
  const float* eb1 = (const float*)d_in[12];
  const float* ew2 = (const float*)d_in[13];
  const float* eb2 = (const float*)d_in[14];
  const float* lng = (const float*)d_in[15];
  const float* lnb = (const float*)d_in[16];
  const float* ow  = (const float*)d_in[17];
  const float* ob  = (const float*)d_in[18];
  char* ws = (char*)d_ws;
  float* Bb   = (float*)(ws + OFF_B);
  float* P0   = (float*)(ws + OFF_P0);   // aliases Bb (dead after conv3)
  float* P1   = (float*)(ws + OFF_P1);
  float* C    = (float*)(ws + OFF_C);
  float* feat = (float*)(ws + OFF_FEAT);
  float* moe  = (float*)(ws + OFF_MOE);
  int*   cnt  = (int*)(ws + OFF_CNT);
  float* gsum = (float*)(ws + OFF_GSUM);
  int*   lrow = (int*)(ws + OFF_LROW);
  float* lgv  = (float*)(ws + OFF_LG);
  float* outp = (float*)d_out;

  // zero moe accumulator + counts + gate sums (contiguous region)
  hipMemsetAsync(ws + OFF_MOE, 0, 4194304 + 128, stream);

  hipLaunchKernelGGL(k_conv12, dim3(4096),    dim3(512), 0, stream, x, c1w, c1b, c2w, c2b, Bb);
  hipLaunchKernelGGL(k_conv3,  dim3(4096, 4), dim3(512), 0, stream, Bb, c3w, c3b, C);
  hipLaunchKernelGGL(k_fc,     dim3(64, 4, 2),dim3(256), 0, stream, C, fcw, P0, P1);
  hipLaunchKernelGGL(k_gate,   dim3(256),     dim3(256), 0, stream, P0, P1, fcb, gw, gb,
                     feat, cnt, gsum, lrow, lgv);
  hipLaunchKernelGGL(k_moe,    dim3(256, 16), dim3(256), 0, stream, feat, ew1, eb1, ew2, eb2,
                     cnt, lrow, lgv, moe);
  hipLaunchKernelGGL(k_lb,     dim3(1),       dim3(64),  0, stream, gsum, outp + (size_t)NB*NCLS);
  hipLaunchKernelGGL(k_ln,     dim3(4096),    dim3(256), 0, stream, feat, moe, lng, lnb);
  hipLaunchKernelGGL(k_out,    dim3(128, 4),  dim3(256), 0, stream, moe, ow, ob, outp);
}